// Round 20
// baseline (16.364 us; speedup 1.0000x reference)
//
#include <hip/hip_runtime.h>

// Depth-4 path signature, N=64, L=512, C=8. Output/batch:
// [sig1(8) | sig2(64) | sig3(512) | sig4(4096)] = 4680 f32.
//
// R20 = R19 (16.34us, best) + packed-FP32 conversion (single mechanism):
//  * phase A fundamental FMAs expressed on ext_vector float2 so clang emits
//    v_pk_fma_f32 (gfx90a+): acc2[l]={accA,accB}[l] (8 pk), s32[m] pairs
//    with b128-loaded dd pairs (4 pk), Cc2={Cc0,Cc1}=dd2[KQ]*w_+s32[KQ]
//    (1 pk, was 2 scalar). Per-step VALU ~35 -> ~23.
//  * same pk treatment in phase B fold (3 pk vs 6) and phase C (3 pk vs 6).
// Everything else byte-identical to R19. Spill discipline: unroll 4 +
// waves_per_eu(4,4).

static constexpr int L = 512;
static constexpr int NC = 8;
static constexpr int SIG = 8 + 64 + 512 + 4096;    // 4680
static constexpr int DXF = 4096;                   // 511*8 zero-padded
static constexpr int SLOTOFF = DXF;                // 4096
static constexpr int SLOT = 592;                   // 8 + 64 + 520 (lvl3 stride 65)
static constexpr int CONTRIB = SLOTOFF + 16 * SLOT;  // 13568
static constexpr int TRANSO = CONTRIB + 16 * 1024;   // 29952
static constexpr int LDSF = TRANSO + 64 * 17 + 16;   // 31056 floats
static constexpr size_t LDS_BYTES = (size_t)LDSF * sizeof(float);  // ~121 KB

using v2f = __attribute__((ext_vector_type(2))) float;
using v4f = __attribute__((ext_vector_type(4))) float;

template <int KQ>
__device__ __forceinline__ void sig_body(float* lds, const float* __restrict__ path,
                                         float* __restrict__ out, const int tid,
                                         const int n) {
    const int w = tid >> 6;          // wave = chunk 0..15
    const int lane = tid & 63;       // (i,j)
    const int i = lane >> 3;
    const int j = lane & 7;

    // ---- wave-local staging: own 256-float dx window, NO block barrier ----
    {
        const float4* pv = reinterpret_cast<const float4*>(path + (size_t)n * (L * NC));
        const int base = w * 64 + lane;              // float4 index, 0..1023
        const float4 a = pv[base];
        const float4 b = pv[min(base + 2, 1023)];
        float4 d;
        d.x = b.x - a.x;
        d.y = b.y - a.y;
        d.z = b.z - a.z;
        d.w = b.w - a.w;
        if (base >= 1022) d = make_float4(0.f, 0.f, 0.f, 0.f);  // seg 511 pad
        *reinterpret_cast<float4*>(&lds[base * 4]) = d;
        asm volatile("" ::: "memory");  // no reordering of phase-A reads above this
    }

    // ---------------- Phase A: branch-free chunk scan (LDS-fed, pk) ------
    float s1 = 0.f, s2 = 0.f;
    v2f s32[4];                       // {s3[2m], s3[2m+1]}
    v2f acc2[8];                      // {accA[l], accB[l]}
#pragma unroll
    for (int m = 0; m < 4; ++m) s32[m] = (v2f){0.f, 0.f};
#pragma unroll
    for (int l = 0; l < 8; ++l) acc2[l] = (v2f){0.f, 0.f};
    constexpr float c3 = 1.f / 6.f;
    constexpr float c4 = 1.f / 24.f;

    const float* dbase = lds + (w * 32) * 8;   // own window only
    const float* bI = dbase + i;   // per-lane di base: 8 addrs, 8 banks, broadcast
    const float* bJ = dbase + j;   // per-lane dj base
#pragma unroll 4
    for (int s = 0; s < 32; ++s) {
        const v4f A = *reinterpret_cast<const v4f*>(dbase + s * 8);
        const v4f B = *reinterpret_cast<const v4f*>(dbase + s * 8 + 4);
        const float di = bI[s * 8];
        const float dj = bJ[s * 8];
        const v2f dd2_0 = __builtin_shufflevector(A, A, 0, 1);
        const v2f dd2_1 = __builtin_shufflevector(A, A, 2, 3);
        const v2f dd2_2 = __builtin_shufflevector(B, B, 0, 1);
        const v2f dd2_3 = __builtin_shufflevector(B, B, 2, 3);

        const float u = fmaf(s1, c3, di * c4);                   // s1/6 + di/24
        const float vv = fmaf(dj, fmaf(di, c3, s1 * 0.5f), s2);  // s2+dj*(s1/2+di/6)
        const float w_ = fmaf(s2, 0.5f, dj * u);                 // s2/2 + dj*u

        // Cc2 = {Cc0, Cc1} = dd2[KQ]*w_ + OLD s32[KQ]   (one pk-FMA)
        const v2f ddKQ = (KQ == 0) ? dd2_0 : (KQ == 1) ? dd2_1 : (KQ == 2) ? dd2_2 : dd2_3;
        const v2f Cc2 = ddKQ * w_ + s32[KQ];

        acc2[0] += A.x * Cc2;
        acc2[1] += A.y * Cc2;
        acc2[2] += A.z * Cc2;
        acc2[3] += A.w * Cc2;
        acc2[4] += B.x * Cc2;
        acc2[5] += B.y * Cc2;
        acc2[6] += B.z * Cc2;
        acc2[7] += B.w * Cc2;
        s32[0] += dd2_0 * vv;
        s32[1] += dd2_1 * vv;
        s32[2] += dd2_2 * vv;
        s32[3] += dd2_3 * vv;

        s2 = fmaf(dj, fmaf(di, 0.5f, s1), s2);
        s1 += di;
    }

    // write chunk lvl1-3 to LDS slot w; lvl3 layout [t1*65 + t2*8 + t3]
    {
        float* sp = lds + SLOTOFF + w * SLOT;
        if (j == 0) sp[i] = s1;
        sp[8 + i * 8 + j] = s2;
        float* s3p = sp + 72 + i * 65 + j * 8;
#pragma unroll
        for (int m = 0; m < 4; ++m) {
            s3p[2 * m] = s32[m].x;
            s3p[2 * m + 1] = s32[m].y;
        }
    }
    __syncthreads();

    // ---------------- Phase B: exclusive prefix fold (Chen, lvl1-3) ------
    float a1 = 0.f, a2 = 0.f;
    v2f a3v = (v2f){0.f, 0.f};
    {
        const float* bp = lds + SLOTOFF;
        for (int b = 0; b < w; ++b, bp += SLOT) {
            const float b1i = bp[i], b1j = bp[j];
            const v2f b1kv = {bp[2 * KQ], bp[2 * KQ + 1]};
            const float b2ij = bp[8 + i * 8 + j];
            const v2f b2jkv = {bp[8 + j * 8 + 2 * KQ], bp[8 + j * 8 + 2 * KQ + 1]};
            const v2f b3v = {bp[72 + i * 65 + j * 8 + 2 * KQ],
                             bp[72 + i * 65 + j * 8 + 2 * KQ + 1]};
            a3v = b1kv * a2 + (b2jkv * a1 + (a3v + b3v));
            a2 = fmaf(a1, b1j, a2 + b2ij);
            a1 += b1i;
        }
    }

    // ---------------- Phase C: contribution -> contrib[w][c*64+lane] -----
    {
        const float* cp = lds + SLOTOFF + w * SLOT;
        float* cb = lds + CONTRIB + w * 1024 + lane;
#pragma unroll
        for (int l = 0; l < 8; ++l) {
            const float b1l = cp[l];
            const v2f b2v = {cp[8 + 16 * KQ + l], cp[8 + 16 * KQ + 8 + l]};
            const v2f b3v = {cp[72 + j * 65 + 16 * KQ + l],
                             cp[72 + j * 65 + 16 * KQ + 8 + l]};
            const v2f v = a3v * b1l + (b2v * a2 + (b3v * a1 + acc2[l]));
            cb[l * 64] = v.x;         // c = 0*8 + l
            cb[(8 + l) * 64] = v.y;   // c = 1*8 + l
        }
    }

    // ---------------- final lvl1-3 (wave 15; lvl3 k-slice per block) -----
    if (w == 15) {
        const float* bp = lds + SLOTOFF + 15 * SLOT;
        const float b1i = bp[i], b1j = bp[j];
        const v2f b1kv = {bp[2 * KQ], bp[2 * KQ + 1]};
        const float b2ij = bp[8 + i * 8 + j];
        const v2f b2jkv = {bp[8 + j * 8 + 2 * KQ], bp[8 + j * 8 + 2 * KQ + 1]};
        const v2f b3v = {bp[72 + i * 65 + j * 8 + 2 * KQ],
                         bp[72 + i * 65 + j * 8 + 2 * KQ + 1]};
        a3v = b1kv * a2 + (b2jkv * a1 + (a3v + b3v));
        a2 = fmaf(a1, b1j, a2 + b2ij);
        a1 += b1i;
        float* o = out + (size_t)n * SIG;
        o[72 + i * 64 + j * 8 + 2 * KQ] = a3v.x;
        o[72 + i * 64 + j * 8 + 2 * KQ + 1] = a3v.y;
        if (KQ == 0) {
            o[8 + i * 8 + j] = a2;
            if (j == 0) o[i] = a1;
        }
    }
    __syncthreads();

    // ------- reduce over w (256 thr x ds_read_b128), stride-17 transpose --
    if (tid < 256) {
        float4 s = make_float4(0.f, 0.f, 0.f, 0.f);
        const float* c0 = lds + CONTRIB + tid * 4;
#pragma unroll
        for (int ww = 0; ww < 16; ++ww) {
            const float4 v = *reinterpret_cast<const float4*>(c0 + ww * 1024);
            s.x += v.x;
            s.y += v.y;
            s.z += v.z;
            s.w += v.w;
        }
        const int c = tid >> 4;           // chunk col 0..15
        const int l0 = (tid * 4) & 63;    // lane row base 0,4,...,60
        float* tp = lds + TRANSO + c;
        tp[(l0 + 0) * 17] = s.x;
        tp[(l0 + 1) * 17] = s.y;
        tp[(l0 + 2) * 17] = s.z;
        tp[(l0 + 3) * 17] = s.w;
    }
    __syncthreads();
    if (tid < 256) {
        const int lp = tid >> 2, cq = tid & 3;
        const float* tp = lds + TRANSO + lp * 17 + cq * 4;
        float4 r;
        r.x = tp[0];
        r.y = tp[1];
        r.z = tp[2];
        r.w = tp[3];
        *reinterpret_cast<float4*>(out + (size_t)n * SIG + 584 + lp * 64 + KQ * 16 + cq * 4) = r;
    }
}

__global__ __launch_bounds__(1024)
__attribute__((amdgpu_waves_per_eu(4, 4)))
void sig_r20(const float* __restrict__ path, float* __restrict__ out) {
    extern __shared__ __align__(16) float lds[];
    const int tid = threadIdx.x;
    const int n = blockIdx.x >> 2;
    switch (blockIdx.x & 3) {
        case 0: sig_body<0>(lds, path, out, tid, n); break;
        case 1: sig_body<1>(lds, path, out, tid, n); break;
        case 2: sig_body<2>(lds, path, out, tid, n); break;
        default: sig_body<3>(lds, path, out, tid, n); break;
    }
}

extern "C" void kernel_launch(void* const* d_in, const int* in_sizes, int n_in,
                              void* d_out, int out_size, void* d_ws, size_t ws_size,
                              hipStream_t stream) {
    const float* path = (const float*)d_in[0];
    float* out = (float*)d_out;
    (void)hipFuncSetAttribute((const void*)sig_r20,
                              hipFuncAttributeMaxDynamicSharedMemorySize,
                              (int)LDS_BYTES);
    // 64 batches x 4 k-quarters = 256 blocks (1 per CU), 1024 threads each
    sig_r20<<<256, 1024, LDS_BYTES, stream>>>(path, out);
}